// Round 1
// baseline (6235.843 us; speedup 1.0000x reference)
//
#include <hip/hip_runtime.h>
#include <hip/hip_bf16.h>

// TemporalAttention fused kernel — Round 1: fp32 correctness baseline.
// One block per (window, branch). grid = 8192, block = 512 (8 waves).
// LDS: XA (x_kv f32 -> later o_pre f32), XB (|x2-x1| f32 -> later kv bf16),
//      Qs (q f32, padded stride 257 -> normalized q), Qn (per-(n,d) head-norms).
// Total LDS = 50176 + 50176 + 50372 + 6468 = 157192 B < 160 KiB.

typedef __attribute__((ext_vector_type(8))) unsigned short ushort8;

#define NTOK 49
#define CDIM 256
#define NHEAD 8
#define HDIM 32
#define KVC 512
#define BWIN 4096
#define QPAD 257   // +1 word pad: lane-per-row scalar reads hit distinct banks
#define NPAD 33    // Qn pad

__device__ __forceinline__ float bfu2f(unsigned short u) {
    return __uint_as_float(((unsigned)u) << 16);
}

__global__ __launch_bounds__(512, 1)
void ta_fused(const float* __restrict__ x1, const float* __restrict__ x2,
              const int* __restrict__ rel_index,
              const float* __restrict__ kv1_w, const float* __restrict__ kv1_b,
              const float* __restrict__ kv2_w, const float* __restrict__ kv2_b,
              const float* __restrict__ q_w,  const float* __restrict__ q_b,
              const float* __restrict__ rpb,
              const float* __restrict__ proj1_w, const float* __restrict__ proj1_b,
              const float* __restrict__ proj2_w, const float* __restrict__ proj2_b,
              float* __restrict__ out)
{
    __shared__ float XA[NTOK * CDIM];
    __shared__ float XB[NTOK * CDIM];
    __shared__ float Qs[NTOK * QPAD];
    __shared__ float Qn[NTOK * NPAD];

    const int t = (int)threadIdx.x;
    const int bb = (int)blockIdx.x;
    const int b = bb >> 1;
    const int branch = bb & 1;
    const float SCALE = 0.17677669529663687f;   // 32^-0.5

    // branch 0: q -> k2/v2, proj1.  branch 1: q*SCALE -> k1/v1, proj2.
    const float* __restrict__ xkv = branch ? x1 : x2;
    const float* __restrict__ xot = branch ? x2 : x1;
    const float* __restrict__ kvw = branch ? kv1_w : kv2_w;
    const float* __restrict__ kvb = branch ? kv1_b : kv2_b;
    const float* __restrict__ pw  = branch ? proj2_w : proj1_w;
    const float* __restrict__ pb  = branch ? proj2_b : proj1_b;
    // l2n over heads is scale-invariant, so normalized q is identical for both
    // branches; the extra SCALE only enters via the "- q" epilogue term.
    const float subscale = branch ? SCALE : 1.0f;
    float* __restrict__ outp = out + (size_t)branch * ((size_t)BWIN * NTOK * CDIM)
                                   + (size_t)b * (NTOK * CDIM);

    // ---- phase 1: XA = x_kv ; XB = |x1 - x2|  (f32, float4-coalesced) ----
    {
        const float4* a4 = (const float4*)(xkv + (size_t)b * (NTOK * CDIM));
        const float4* o4 = (const float4*)(xot + (size_t)b * (NTOK * CDIM));
        float4* XA4 = (float4*)XA;
        float4* XB4 = (float4*)XB;
        for (int i = t; i < NTOK * CDIM / 4; i += 512) {
            float4 a = a4[i];
            float4 o = o4[i];
            XA4[i] = a;
            XB4[i] = make_float4(fabsf(a.x - o.x), fabsf(a.y - o.y),
                                 fabsf(a.z - o.z), fabsf(a.w - o.w));
        }
    }
    __syncthreads();

    // ---- phase 2: Qs = (XB @ q_w^T + q_b) * SCALE ----
    // thread (j = t&255, row-half = t>>8); LDS x-reads are wave-uniform broadcasts
    {
        const int j  = t & 255;
        const int rh = t >> 8;
        const int n0 = rh * 25;
        const int nr = rh ? 24 : 25;          // rows 0..24 / 25..48 (wave-uniform)
        float acc[25];
#pragma unroll
        for (int r = 0; r < 25; ++r) acc[r] = 0.f;
        const float4* wrow = (const float4*)(q_w + (size_t)j * CDIM);
        for (int kc = 0; kc < CDIM / 4; ++kc) {
            float4 w = wrow[kc];
#pragma unroll
            for (int r = 0; r < 25; ++r) {
                if (r < nr) {
                    float4 xv = *(const float4*)&XB[(n0 + r) * CDIM + kc * 4];
                    acc[r] = fmaf(xv.x, w.x, acc[r]);
                    acc[r] = fmaf(xv.y, w.y, acc[r]);
                    acc[r] = fmaf(xv.z, w.z, acc[r]);
                    acc[r] = fmaf(xv.w, w.w, acc[r]);
                }
            }
        }
        const float bj = q_b[j];
#pragma unroll
        for (int r = 0; r < 25; ++r)
            if (r < nr) Qs[(n0 + r) * QPAD + j] = (acc[r] + bj) * SCALE;
    }
    __syncthreads();

    // ---- phase 3: XB <- bf16 kv = XA @ kvw^T + kvb   [49][512] ----
    {
        __hip_bfloat16* KV = (__hip_bfloat16*)XB;
        const int j = t;                       // 512 threads <-> 512 columns
        float acc[NTOK];
#pragma unroll
        for (int r = 0; r < NTOK; ++r) acc[r] = 0.f;
        const float4* wrow = (const float4*)(kvw + (size_t)j * CDIM);
        for (int kc = 0; kc < CDIM / 4; ++kc) {
            float4 w = wrow[kc];
#pragma unroll
            for (int r = 0; r < NTOK; ++r) {
                float4 xv = *(const float4*)&XA[r * CDIM + kc * 4];
                acc[r] = fmaf(xv.x, w.x, acc[r]);
                acc[r] = fmaf(xv.y, w.y, acc[r]);
                acc[r] = fmaf(xv.z, w.z, acc[r]);
                acc[r] = fmaf(xv.w, w.w, acc[r]);
            }
        }
        const float bj = kvb[j];
#pragma unroll
        for (int r = 0; r < NTOK; ++r)
            KV[r * KVC + j] = __float2bfloat16(acc[r] + bj);
    }
    __syncthreads();

    // ---- phase 4: l2-normalize over HEADS (axis=1 of [B,H,N,D]) ----
    for (int p = t; p < NTOK * HDIM; p += 512) {
        const int n = p >> 5;
        const int d = p & 31;
        float s = 0.f;
        float qv[NHEAD];
#pragma unroll
        for (int h = 0; h < NHEAD; ++h) {
            qv[h] = Qs[n * QPAD + h * HDIM + d];
            s = fmaf(qv[h], qv[h], s);
        }
        const float nrm = fmaxf(sqrtf(s), 1e-12f);
        const float inv = 1.0f / nrm;
        Qn[n * NPAD + d] = nrm;               // keep norm: qraw = qn * nrm
#pragma unroll
        for (int h = 0; h < NHEAD; ++h)
            Qs[n * QPAD + h * HDIM + d] = qv[h] * inv;
    }
    {
        __hip_bfloat16* KV = (__hip_bfloat16*)XB;
        for (int p = t; p < NTOK * HDIM; p += 512) {
            const int m = p >> 5;
            const int d = p & 31;
            float s = 0.f;
            float kv[NHEAD];
#pragma unroll
            for (int h = 0; h < NHEAD; ++h) {
                kv[h] = __bfloat162float(KV[m * KVC + h * HDIM + d]);
                s = fmaf(kv[h], kv[h], s);
            }
            const float inv = 1.0f / fmaxf(sqrtf(s), 1e-12f);
#pragma unroll
            for (int h = 0; h < NHEAD; ++h)
                KV[m * KVC + h * HDIM + d] = __float2bfloat16(kv[h] * inv);
        }
    }
    __syncthreads();

    // ---- phase 5: attention, one wave per head, lane-per-row, online softmax ----
    {
        const int h  = t >> 6;
        const int ln = t & 63;
        const unsigned short* KV = (const unsigned short*)XB;
        if (ln < NTOK) {
            float qf[HDIM];
#pragma unroll
            for (int d = 0; d < HDIM; ++d)
                qf[d] = Qs[ln * QPAD + h * HDIM + d];   // stride-257 words: conflict-free

            float o[HDIM];
#pragma unroll
            for (int d = 0; d < HDIM; ++d) o[d] = 0.f;
            float mx  = -3.0e38f;
            float sum = 0.f;

            const int* __restrict__ ri = rel_index + ln * NTOK;
            for (int m = 0; m < NTOK; ++m) {
                // logits: qn . kn  (k-row reads are wave-uniform b128 broadcasts)
                const ushort8* krow = (const ushort8*)(KV + m * KVC + h * HDIM);
                float s = 0.f;
#pragma unroll
                for (int g = 0; g < 4; ++g) {
                    ushort8 k8 = krow[g];
#pragma unroll
                    for (int e = 0; e < 8; ++e)
                        s = fmaf(qf[g * 8 + e], bfu2f(k8[e]), s);
                }
                s += rpb[ri[m] * NHEAD + h];   // relative position bias (L1-hot)

                // online softmax update
                const float nm = fmaxf(mx, s);
                const float c  = __expf(mx - nm);   // first iter: exp(-inf)=0
                const float pr = __expf(s - nm);
                sum = fmaf(sum, c, pr);
                mx = nm;

                const ushort8* vrow = (const ushort8*)(KV + m * KVC + CDIM + h * HDIM);
#pragma unroll
                for (int g = 0; g < 4; ++g) {
                    ushort8 v8 = vrow[g];
#pragma unroll
                    for (int e = 0; e < 8; ++e) {
                        const int d = g * 8 + e;
                        o[d] = fmaf(o[d], c, pr * bfu2f(v8[e]));
                    }
                }
            }
            const float isum = 1.0f / sum;
            // o_pre = attn@v - q_raw*subscale ; q_raw = qn * stored norm
#pragma unroll
            for (int d = 0; d < HDIM; ++d) {
                const float qraw = Qs[ln * QPAD + h * HDIM + d] * Qn[ln * NPAD + d];
                o[d] = fmaf(o[d], isum, -qraw * subscale);
            }
            float4* orow = (float4*)&XA[ln * CDIM + h * HDIM];
#pragma unroll
            for (int g = 0; g < 8; ++g)
                orow[g] = make_float4(o[g*4+0], o[g*4+1], o[g*4+2], o[g*4+3]);
        }
    }
    __syncthreads();

    // ---- phase 6: out = XA @ pw^T + pb  (coalesced f32 stores) ----
    {
        const int j  = t & 255;
        const int rh = t >> 8;
        const int n0 = rh * 25;
        const int nr = rh ? 24 : 25;
        float acc[25];
#pragma unroll
        for (int r = 0; r < 25; ++r) acc[r] = 0.f;
        const float4* wrow = (const float4*)(pw + (size_t)j * CDIM);
        for (int kc = 0; kc < CDIM / 4; ++kc) {
            float4 w = wrow[kc];
#pragma unroll
            for (int r = 0; r < 25; ++r) {
                if (r < nr) {
                    float4 xv = *(const float4*)&XA[(n0 + r) * CDIM + kc * 4];
                    acc[r] = fmaf(xv.x, w.x, acc[r]);
                    acc[r] = fmaf(xv.y, w.y, acc[r]);
                    acc[r] = fmaf(xv.z, w.z, acc[r]);
                    acc[r] = fmaf(xv.w, w.w, acc[r]);
                }
            }
        }
        const float bj = pb[j];
#pragma unroll
        for (int r = 0; r < 25; ++r)
            if (r < nr) outp[(n0 + r) * CDIM + j] = acc[r] + bj;
    }
}

extern "C" void kernel_launch(void* const* d_in, const int* in_sizes, int n_in,
                              void* d_out, int out_size, void* d_ws, size_t ws_size,
                              hipStream_t stream) {
    (void)in_sizes; (void)n_in; (void)d_ws; (void)ws_size; (void)out_size;
    const float* x1   = (const float*)d_in[0];
    const float* x2   = (const float*)d_in[1];
    const int*   rel  = (const int*)  d_in[2];
    const float* kv1w = (const float*)d_in[3];
    const float* kv1b = (const float*)d_in[4];
    const float* kv2w = (const float*)d_in[5];
    const float* kv2b = (const float*)d_in[6];
    const float* qw   = (const float*)d_in[7];
    const float* qb   = (const float*)d_in[8];
    const float* rpb  = (const float*)d_in[9];
    const float* p1w  = (const float*)d_in[10];
    const float* p1b  = (const float*)d_in[11];
    const float* p2w  = (const float*)d_in[12];
    const float* p2b  = (const float*)d_in[13];
    float* out = (float*)d_out;

    hipLaunchKernelGGL(ta_fused, dim3(BWIN * 2), dim3(512), 0, stream,
                       x1, x2, rel, kv1w, kv1b, kv2w, kv2b, qw, qb, rpb,
                       p1w, p1b, p2w, p2b, out);
}

// Round 2
// 2807.362 us; speedup vs baseline: 2.2212x; 2.2212x over previous
//
#include <hip/hip_runtime.h>
#include <hip/hip_bf16.h>

// TemporalAttention — Round 2: full MFMA rewrite.
// One block per window (both branches), 256 threads = 4 waves, wave w owns M-tile w.
// LDS 160 KiB exactly: XA, XD, QN, KN [64][256] bf16 swizzled + VT [256][64] bf16 swizzled.
// All GEMMs m-split => head-axis l2-normalization is lane-local on C-frags.
// Weights pre-converted f32->bf16 into d_ws by prep kernel.

typedef __attribute__((ext_vector_type(8))) short short8;
typedef __attribute__((ext_vector_type(4))) float f32x4;

#define NTOK 49
#define BWIN 4096
#define SCALE 0.17677669529663687f

// d_ws bf16 weight offsets (elements)
#define OFF_Q   0
#define OFF_KV1 65536
#define OFF_KV2 196608
#define OFF_P1  327680
#define OFF_P2  393216
#define TOT_W   458752

__device__ __forceinline__ short f2b(float f) {
    union { float f; unsigned u; } v{f};
    unsigned r = v.u + 0x7fffu + ((v.u >> 16) & 1u);   // RNE, inputs never NaN
    return (short)(r >> 16);
}
__device__ __forceinline__ float b2f(short s) {
    return __uint_as_float(((unsigned)(unsigned short)s) << 16);
}
__device__ __forceinline__ short8 pack8(float4 a, float4 b) {
    short8 s;
    s[0]=f2b(a.x); s[1]=f2b(a.y); s[2]=f2b(a.z); s[3]=f2b(a.w);
    s[4]=f2b(b.x); s[5]=f2b(b.y); s[6]=f2b(b.z); s[7]=f2b(b.w);
    return s;
}
__device__ __forceinline__ f32x4 mfma16(short8 a, short8 b, f32x4 c) {
    return __builtin_amdgcn_mfma_f32_16x16x32_bf16(a, b, c, 0, 0, 0);
}
// row-major [64][256] bf16, XOR-swizzled (T2): 16B chunk at (row, c8), c8 % 8 == 0
__device__ __forceinline__ short8 ld16(const short* base, int row, int c8) {
    return *(const short8*)((const char*)base + row*512 + ((c8*2) ^ ((row&7)<<4)));
}
__device__ __forceinline__ void st2(short* base, int row, int c, short v) {
    *(short*)((char*)base + row*512 + ((c*2) ^ ((row&7)<<4))) = v;
}
// 128B-stride rows (VT [256][64], P [16][64])
__device__ __forceinline__ short8 ld16r128(const short* base, int row, int m8) {
    return *(const short8*)((const char*)base + row*128 + ((m8*2) ^ ((row&7)<<4)));
}
__device__ __forceinline__ void st2r128(short* base, int row, int m, short v) {
    *(short*)((char*)base + row*128 + ((m*2) ^ ((row&7)<<4))) = v;
}
__device__ __forceinline__ short8 g16(const short* p) { return *(const short8*)p; }

__global__ void prep_w(const float* __restrict__ qw, const float* __restrict__ kv1,
                       const float* __restrict__ kv2, const float* __restrict__ p1,
                       const float* __restrict__ p2, short* __restrict__ ws) {
    int i = blockIdx.x * 256 + threadIdx.x;
    float v;
    if      (i < OFF_KV1) v = qw[i];
    else if (i < OFF_KV2) v = kv1[i - OFF_KV1];
    else if (i < OFF_P1)  v = kv2[i - OFF_KV2];
    else if (i < OFF_P2)  v = p1[i - OFF_P1];
    else                  v = p2[i - OFF_P2];
    ws[i] = f2b(v);
}

__global__ __launch_bounds__(256, 1)
void ta_mfma(const float* __restrict__ x1, const float* __restrict__ x2,
             const int* __restrict__ rel_index,
             const float* __restrict__ kv1_b, const float* __restrict__ kv2_b,
             const float* __restrict__ q_b,  const float* __restrict__ rpb,
             const float* __restrict__ p1_b, const float* __restrict__ p2_b,
             const short* __restrict__ wsbf, float* __restrict__ out)
{
    __shared__ short XA[64*256];   // x_kv bf16 -> o_pre
    __shared__ short XD[64*256];   // |x2-x1| -> P scratch (2KB/wave)
    __shared__ short QN[64*256];   // normalized q
    __shared__ short KN[64*256];   // normalized k
    __shared__ short VT[256*64];   // v transposed [c][m]

    const int t  = (int)threadIdx.x;
    const int w  = t >> 6;          // wave = M-tile
    const int lr = t & 15;          // lane&15
    const int lg = (t >> 4) & 3;    // (lane>>4)&3
    const int b  = (int)blockIdx.x;
    const size_t xb = (size_t)b * (NTOK*256);

    // ---- stage: XA = bf16(x2), XD = bf16(|x2-x1|), rows 49..63 zero ----
#pragma unroll
    for (int it = 0; it < 8; ++it) {
        int chunk = t + it*256, row = chunk >> 5, ch = chunk & 31;
        short8 sa = {0,0,0,0,0,0,0,0}, sd = {0,0,0,0,0,0,0,0};
        if (row < NTOK) {
            const float* pa = x2 + xb + row*256 + ch*8;
            const float* pc = x1 + xb + row*256 + ch*8;
            float4 a0 = *(const float4*)pa, a1 = *(const float4*)(pa+4);
            float4 c0 = *(const float4*)pc, c1 = *(const float4*)(pc+4);
            sa = pack8(a0, a1);
            float4 d0 = make_float4(fabsf(a0.x-c0.x), fabsf(a0.y-c0.y),
                                    fabsf(a0.z-c0.z), fabsf(a0.w-c0.w));
            float4 d1 = make_float4(fabsf(a1.x-c1.x), fabsf(a1.y-c1.y),
                                    fabsf(a1.z-c1.z), fabsf(a1.w-c1.w));
            sd = pack8(d0, d1);
        }
        int byt = row*512 + ((ch*16) ^ ((row&7)<<4));
        *(short8*)((char*)XA + byt) = sa;
        *(short8*)((char*)XD + byt) = sd;
    }
    __syncthreads();

    // ---- q GEMM (m-split): qa = (XD @ qw^T + qb) * SCALE; lane-local head-norm ----
    float nrm[4][2];
    {
        short8 a[8];
#pragma unroll
        for (int kb = 0; kb < 8; ++kb) a[kb] = ld16(XD, 16*w + lr, kb*32 + lg*8);
        f32x4 qa[16];
        const short* wq = wsbf + OFF_Q;
#pragma unroll
        for (int t16 = 0; t16 < 16; ++t16) {
            const short* bp = wq + (t16*16 + lr)*256 + lg*8;
            f32x4 acc = {0.f,0.f,0.f,0.f};
#pragma unroll
            for (int kb = 0; kb < 8; ++kb) acc = mfma16(a[kb], g16(bp + kb*32), acc);
            float bj = q_b[t16*16 + lr];
#pragma unroll
            for (int r = 0; r < 4; ++r) acc[r] = (acc[r] + bj) * SCALE;
            qa[t16] = acc;
        }
        float rin[4][2];
#pragma unroll
        for (int r = 0; r < 4; ++r)
#pragma unroll
            for (int p = 0; p < 2; ++p) {
                float s = 0.f;
#pragma unroll
                for (int j = 0; j < 8; ++j) { float v = qa[2*j+p][r]; s = fmaf(v, v, s); }
                float nr = fmaxf(sqrtf(s), 1e-12f);
                nrm[r][p] = nr; rin[r][p] = 1.0f / nr;
            }
#pragma unroll
        for (int t16 = 0; t16 < 16; ++t16) {
            int p = t16 & 1;
#pragma unroll
            for (int r = 0; r < 4; ++r)
                st2(QN, 16*w + 4*lg + r, 16*t16 + lr, f2b(qa[t16][r] * rin[r][p]));
        }
    }

    // rel_index for this wave's rows (shared across branches/heads)
    int ri_[4][4];
#pragma unroll
    for (int nt = 0; nt < 4; ++nt)
#pragma unroll
        for (int r = 0; r < 4; ++r) {
            int n = 16*w + 4*lg + r, mc = 16*nt + lr;
            ri_[nt][r] = (n < NTOK && mc < NTOK) ? rel_index[n*NTOK + mc] : -1;
        }

#pragma unroll 1
    for (int branch = 0; branch < 2; ++branch) {
        const short* wkv = wsbf + (branch ? OFF_KV1 : OFF_KV2);
        const float* kvb = branch ? kv1_b : kv2_b;
        const short* wpj = wsbf + (branch ? OFF_P2 : OFF_P1);
        const float* pjb = branch ? p2_b : p1_b;
        const float subscale = branch ? SCALE : 1.0f;
        float* outp = out + (size_t)branch * ((size_t)BWIN*NTOK*256) + (size_t)b*(NTOK*256);

        if (branch == 1) {
            __syncthreads();           // P5(br0) done reading XA
#pragma unroll
            for (int it = 0; it < 8; ++it) {
                int chunk = t + it*256, row = chunk >> 5, ch = chunk & 31;
                short8 sa = {0,0,0,0,0,0,0,0};
                if (row < NTOK) {
                    const float* pa = x1 + xb + row*256 + ch*8;
                    float4 a0 = *(const float4*)pa, a1 = *(const float4*)(pa+4);
                    sa = pack8(a0, a1);
                }
                *(short8*)((char*)XA + row*512 + ((ch*16) ^ ((row&7)<<4))) = sa;
            }
            __syncthreads();
        }

        // ---- KN GEMM (m-split) + lane-local head-norm ----
        {
            short8 a[8];
#pragma unroll
            for (int kb = 0; kb < 8; ++kb) a[kb] = ld16(XA, 16*w + lr, kb*32 + lg*8);
            f32x4 ka[16];
#pragma unroll
            for (int t16 = 0; t16 < 16; ++t16) {
                const short* bp = wkv + (t16*16 + lr)*256 + lg*8;
                f32x4 acc = {0.f,0.f,0.f,0.f};
#pragma unroll
                for (int kb = 0; kb < 8; ++kb) acc = mfma16(a[kb], g16(bp + kb*32), acc);
                float bj = kvb[t16*16 + lr];
#pragma unroll
                for (int r = 0; r < 4; ++r) acc[r] += bj;
                ka[t16] = acc;
            }
#pragma unroll
            for (int r = 0; r < 4; ++r)
#pragma unroll
                for (int p = 0; p < 2; ++p) {
                    float s = 0.f;
#pragma unroll
                    for (int j = 0; j < 8; ++j) { float v = ka[2*j+p][r]; s = fmaf(v, v, s); }
                    float rv = 1.0f / fmaxf(sqrtf(s), 1e-12f);
#pragma unroll
                    for (int j = 0; j < 8; ++j)
                        st2(KN, 16*w + 4*lg + r, 16*(2*j+p) + lr, f2b(ka[2*j+p][r] * rv));
                }
        }

        // ---- VT GEMM (transposed: V^T = Wv @ X^T), c-split across waves ----
        {
            short8 bx[4][8];
#pragma unroll
            for (int mt = 0; mt < 4; ++mt)
#pragma unroll
                for (int kb = 0; kb < 8; ++kb) bx[mt][kb] = ld16(XA, 16*mt + lr, kb*32 + lg*8);
#pragma unroll
            for (int ct = 0; ct < 4; ++ct) {
                int c0 = (4*w + ct) * 16;
                const short* ap = wkv + (256 + c0 + lr)*256 + lg*8;
                short8 aw[8];
#pragma unroll
                for (int kb = 0; kb < 8; ++kb) aw[kb] = g16(ap + kb*32);
                float4 bv4 = *(const float4*)(kvb + 256 + c0 + 4*lg);
                float bvr[4] = {bv4.x, bv4.y, bv4.z, bv4.w};
#pragma unroll
                for (int mt = 0; mt < 4; ++mt) {
                    f32x4 acc = {0.f,0.f,0.f,0.f};
#pragma unroll
                    for (int kb = 0; kb < 8; ++kb) acc = mfma16(aw[kb], bx[mt][kb], acc);
                    int m = 16*mt + lr;
                    bool val = m < NTOK;
#pragma unroll
                    for (int r = 0; r < 4; ++r)
                        st2r128(VT, c0 + 4*lg + r, m, f2b(val ? (acc[r] + bvr[r]) : 0.f));
                }
            }
        }
        __syncthreads();

        // ---- attention: QK^T -> masked softmax -> PV -> -q epilogue -> XA(o_pre) ----
        {
            short* Pb = (short*)((char*)XD + w*2048);
#pragma unroll 1
            for (int h = 0; h < 8; ++h) {
                short8 aq = ld16(QN, 16*w + lr, h*32 + lg*8);
                f32x4 s[4];
#pragma unroll
                for (int nt = 0; nt < 4; ++nt) {
                    f32x4 z = {0.f,0.f,0.f,0.f};
                    s[nt] = mfma16(aq, ld16(KN, 16*nt + lr, h*32 + lg*8), z);
                }
                float sv[4][4];
#pragma unroll
                for (int nt = 0; nt < 4; ++nt) {
                    bool msk = (16*nt + lr) >= NTOK;
#pragma unroll
                    for (int r = 0; r < 4; ++r) {
                        float bi = (ri_[nt][r] >= 0) ? rpb[ri_[nt][r]*8 + h] : 0.f;
                        sv[nt][r] = msk ? -1e30f : (s[nt][r] + bi);
                    }
                }
                float isum[4];
#pragma unroll
                for (int r = 0; r < 4; ++r) {
                    float mx = fmaxf(fmaxf(sv[0][r], sv[1][r]), fmaxf(sv[2][r], sv[3][r]));
#pragma unroll
                    for (int d = 1; d < 16; d <<= 1) mx = fmaxf(mx, __shfl_xor(mx, d));
                    float e0 = __expf(sv[0][r]-mx), e1 = __expf(sv[1][r]-mx);
                    float e2 = __expf(sv[2][r]-mx), e3 = __expf(sv[3][r]-mx);
                    float sm = (e0+e1) + (e2+e3);
#pragma unroll
                    for (int d = 1; d < 16; d <<= 1) sm += __shfl_xor(sm, d);
                    isum[r] = 1.0f / sm;
                    int pr = 4*lg + r;
                    st2r128(Pb, pr,      lr, f2b(e0));
                    st2r128(Pb, pr, 16 + lr, f2b(e1));
                    st2r128(Pb, pr, 32 + lr, f2b(e2));
                    st2r128(Pb, pr, 48 + lr, f2b(e3));
                }
                short8 pa0 = ld16r128(Pb, lr, lg*8);
                short8 pa1 = ld16r128(Pb, lr, 32 + lg*8);
#pragma unroll
                for (int nt2 = 0; nt2 < 2; ++nt2) {
                    int crow = h*32 + 16*nt2 + lr;
                    f32x4 acc = {0.f,0.f,0.f,0.f};
                    acc = mfma16(pa0, ld16r128(VT, crow, lg*8), acc);
                    acc = mfma16(pa1, ld16r128(VT, crow, 32 + lg*8), acc);
#pragma unroll
                    for (int r = 0; r < 4; ++r) {
                        int m = 16*w + 4*lg + r, c = h*32 + 16*nt2 + lr;
                        float qn_ = b2f(*(const short*)((const char*)QN + m*512 + ((c*2) ^ ((m&7)<<4))));
                        float o = acc[r]*isum[r] - qn_*nrm[r][nt2]*subscale;
                        st2(XA, m, c, f2b(o));
                    }
                }
            }
        }
        __syncthreads();

        // ---- proj GEMM (m-split): out = XA(o_pre) @ pw^T + pb ----
        {
            short8 a[8];
#pragma unroll
            for (int kb = 0; kb < 8; ++kb) a[kb] = ld16(XA, 16*w + lr, kb*32 + lg*8);
#pragma unroll
            for (int t16 = 0; t16 < 16; ++t16) {
                const short* bp = wpj + (t16*16 + lr)*256 + lg*8;
                f32x4 acc = {0.f,0.f,0.f,0.f};
#pragma unroll
                for (int kb = 0; kb < 8; ++kb) acc = mfma16(a[kb], g16(bp + kb*32), acc);
                float bj = pjb[t16*16 + lr];
#pragma unroll
                for (int r = 0; r < 4; ++r) {
                    int m = 16*w + 4*lg + r;
                    if (m < NTOK) outp[(size_t)m*256 + 16*t16 + lr] = acc[r] + bj;
                }
            }
        }
    }
}

extern "C" void kernel_launch(void* const* d_in, const int* in_sizes, int n_in,
                              void* d_out, int out_size, void* d_ws, size_t ws_size,
                              hipStream_t stream) {
    (void)in_sizes; (void)n_in; (void)ws_size; (void)out_size;
    const float* x1   = (const float*)d_in[0];
    const float* x2   = (const float*)d_in[1];
    const int*   rel  = (const int*)  d_in[2];
    const float* kv1w = (const float*)d_in[3];
    const float* kv1b = (const float*)d_in[4];
    const float* kv2w = (const float*)d_in[5];
    const float* kv2b = (const float*)d_in[6];
    const float* qw   = (const float*)d_in[7];
    const float* qb   = (const float*)d_in[8];
    const float* rpb  = (const float*)d_in[9];
    const float* p1w  = (const float*)d_in[10];
    const float* p1b  = (const float*)d_in[11];
    const float* p2w  = (const float*)d_in[12];
    const float* p2b  = (const float*)d_in[13];
    float* out = (float*)d_out;
    short* ws  = (short*)d_ws;

    hipLaunchKernelGGL(prep_w, dim3(TOT_W/256), dim3(256), 0, stream,
                       qw, kv1w, kv2w, p1w, p2w, ws);
    hipLaunchKernelGGL(ta_mfma, dim3(BWIN), dim3(256), 0, stream,
                       x1, x2, rel, kv1b, kv2b, qb, rpb, p1b, p2b,
                       (const short*)ws, out);
}

// Round 3
// 2344.125 us; speedup vs baseline: 2.6602x; 1.1976x over previous
//
#include <hip/hip_runtime.h>
#include <hip/hip_bf16.h>

// TemporalAttention — Round 3: occupancy. 512 threads = 8 waves = 2 waves/SIMD.
// Wave w: wm = w&3 (M-tile), wn = w>>2 (half). q/k GEMMs split by t16 parity so
// the cross-head l2-norm stays lane-local; norms round-trip via 8KB f32 LDS
// (dead XD region). VT split 2 col-tiles/wave, attention 4 heads/wave.
// LDS unchanged: 5 x [64][256] bf16 swizzled = 160 KiB.

typedef __attribute__((ext_vector_type(8))) short short8;
typedef __attribute__((ext_vector_type(4))) float f32x4;

#define NTOK 49
#define BWIN 4096
#define SCALE 0.17677669529663687f

#define OFF_Q   0
#define OFF_KV1 65536
#define OFF_KV2 196608
#define OFF_P1  327680
#define OFF_P2  393216
#define TOT_W   458752

__device__ __forceinline__ short f2b(float f) {
    union { float f; unsigned u; } v{f};
    unsigned r = v.u + 0x7fffu + ((v.u >> 16) & 1u);   // RNE, inputs never NaN
    return (short)(r >> 16);
}
__device__ __forceinline__ float b2f(short s) {
    return __uint_as_float(((unsigned)(unsigned short)s) << 16);
}
__device__ __forceinline__ short8 pack8(float4 a, float4 b) {
    short8 s;
    s[0]=f2b(a.x); s[1]=f2b(a.y); s[2]=f2b(a.z); s[3]=f2b(a.w);
    s[4]=f2b(b.x); s[5]=f2b(b.y); s[6]=f2b(b.z); s[7]=f2b(b.w);
    return s;
}
__device__ __forceinline__ f32x4 mfma16(short8 a, short8 b, f32x4 c) {
    return __builtin_amdgcn_mfma_f32_16x16x32_bf16(a, b, c, 0, 0, 0);
}
// row-major [64][256] bf16, XOR-swizzled: 16B chunk at (row, c8)
__device__ __forceinline__ short8 ld16(const short* base, int row, int c8) {
    return *(const short8*)((const char*)base + row*512 + ((c8*2) ^ ((row&7)<<4)));
}
__device__ __forceinline__ void st2(short* base, int row, int c, short v) {
    *(short*)((char*)base + row*512 + ((c*2) ^ ((row&7)<<4))) = v;
}
// 128B-stride rows (VT [256][64], P [16][64])
__device__ __forceinline__ short8 ld16r128(const short* base, int row, int m8) {
    return *(const short8*)((const char*)base + row*128 + ((m8*2) ^ ((row&7)<<4)));
}
__device__ __forceinline__ void st2r128(short* base, int row, int m, short v) {
    *(short*)((char*)base + row*128 + ((m*2) ^ ((row&7)<<4))) = v;
}
__device__ __forceinline__ short8 g16(const short* p) { return *(const short8*)p; }

__global__ void prep_w(const float* __restrict__ qw, const float* __restrict__ kv1,
                       const float* __restrict__ kv2, const float* __restrict__ p1,
                       const float* __restrict__ p2, short* __restrict__ ws) {
    int i = blockIdx.x * 256 + threadIdx.x;
    float v;
    if      (i < OFF_KV1) v = qw[i];
    else if (i < OFF_KV2) v = kv1[i - OFF_KV1];
    else if (i < OFF_P1)  v = kv2[i - OFF_KV2];
    else if (i < OFF_P2)  v = p1[i - OFF_P1];
    else                  v = p2[i - OFF_P2];
    ws[i] = f2b(v);
}

__global__ __launch_bounds__(512, 2)
void ta_mfma(const float* __restrict__ x1, const float* __restrict__ x2,
             const int* __restrict__ rel_index,
             const float* __restrict__ kv1_b, const float* __restrict__ kv2_b,
             const float* __restrict__ q_b,  const float* __restrict__ rpb,
             const float* __restrict__ p1_b, const float* __restrict__ p2_b,
             const short* __restrict__ wsbf, float* __restrict__ out)
{
    __shared__ short XA[64*256];   // x_kv bf16 -> o_pre
    __shared__ short XD[64*256];   // |x2-x1| -> Qn f32 (8KB) + P scratch (8K..24K)
    __shared__ short QN[64*256];   // normalized q
    __shared__ short KN[64*256];   // normalized k
    __shared__ short VT[256*64];   // v transposed [c][m]

    const int t  = (int)threadIdx.x;
    const int w  = t >> 6;
    const int wm = w & 3;           // M-tile
    const int wn = w >> 2;          // half (t16 parity / head half / etc.)
    const int lr = t & 15;
    const int lg = (t >> 4) & 3;
    const int b  = (int)blockIdx.x;
    const size_t xb = (size_t)b * (NTOK*256);

    float* Qn_lds = (float*)XD;                   // [64][32] f32 = 8 KB

    // ---- stage: XA = bf16(x2), XD = bf16(|x2-x1|) ----
#pragma unroll
    for (int it = 0; it < 4; ++it) {
        int chunk = t + it*512, row = chunk >> 5, ch = chunk & 31;
        short8 sa = {0,0,0,0,0,0,0,0}, sd = {0,0,0,0,0,0,0,0};
        if (row < NTOK) {
            const float* pa = x2 + xb + row*256 + ch*8;
            const float* pc = x1 + xb + row*256 + ch*8;
            float4 a0 = *(const float4*)pa, a1 = *(const float4*)(pa+4);
            float4 c0 = *(const float4*)pc, c1 = *(const float4*)(pc+4);
            sa = pack8(a0, a1);
            float4 d0 = make_float4(fabsf(a0.x-c0.x), fabsf(a0.y-c0.y),
                                    fabsf(a0.z-c0.z), fabsf(a0.w-c0.w));
            float4 d1 = make_float4(fabsf(a1.x-c1.x), fabsf(a1.y-c1.y),
                                    fabsf(a1.z-c1.z), fabsf(a1.w-c1.w));
            sd = pack8(d0, d1);
        }
        int byt = row*512 + ((ch*16) ^ ((row&7)<<4));
        *(short8*)((char*)XA + byt) = sa;
        *(short8*)((char*)XD + byt) = sd;
    }
    __syncthreads();

    // ---- q GEMM: t16 = 2j+wn (parity split => lane-local head-norm) ----
    {
        short8 a[8];
#pragma unroll
        for (int kb = 0; kb < 8; ++kb) a[kb] = ld16(XD, 16*wm + lr, kb*32 + lg*8);
        __syncthreads();                          // XD rows 0..15 become Qn

        f32x4 qa[8];
        const short* wq = wsbf + OFF_Q;
#pragma unroll
        for (int j = 0; j < 8; ++j) {
            const int t16 = 2*j + wn;
            const short* bp = wq + (t16*16 + lr)*256 + lg*8;
            f32x4 acc = {0.f,0.f,0.f,0.f};
#pragma unroll
            for (int kb = 0; kb < 8; ++kb) acc = mfma16(a[kb], g16(bp + kb*32), acc);
            float bj = q_b[t16*16 + lr];
#pragma unroll
            for (int r = 0; r < 4; ++r) acc[r] = (acc[r] + bj) * SCALE;
            qa[j] = acc;
        }
        float rin[4];
#pragma unroll
        for (int r = 0; r < 4; ++r) {
            float s = 0.f;
#pragma unroll
            for (int j = 0; j < 8; ++j) { float v = qa[j][r]; s = fmaf(v, v, s); }
            float nr = fmaxf(sqrtf(s), 1e-12f);
            Qn_lds[(16*wm + 4*lg + r)*32 + 16*wn + lr] = nr;
            rin[r] = 1.0f / nr;
        }
#pragma unroll
        for (int j = 0; j < 8; ++j)
#pragma unroll
            for (int r = 0; r < 4; ++r)
                st2(QN, 16*wm + 4*lg + r, 32*j + 16*wn + lr, f2b(qa[j][r] * rin[r]));
    }

    // rel_index for this wave's rows
    int ri_[4][4];
#pragma unroll
    for (int nt = 0; nt < 4; ++nt)
#pragma unroll
        for (int r = 0; r < 4; ++r) {
            int n = 16*wm + 4*lg + r, mc = 16*nt + lr;
            ri_[nt][r] = (n < NTOK && mc < NTOK) ? rel_index[n*NTOK + mc] : -1;
        }

#pragma unroll 1
    for (int branch = 0; branch < 2; ++branch) {
        const short* wkv = wsbf + (branch ? OFF_KV1 : OFF_KV2);
        const float* kvb = branch ? kv1_b : kv2_b;
        const short* wpj = wsbf + (branch ? OFF_P2 : OFF_P1);
        const float* pjb = branch ? p2_b : p1_b;
        const float subscale = branch ? SCALE : 1.0f;
        float* outp = out + (size_t)branch * ((size_t)BWIN*NTOK*256) + (size_t)b*(NTOK*256);

        if (branch == 1) {
            __syncthreads();           // proj(br0) done reading XA
#pragma unroll
            for (int it = 0; it < 4; ++it) {
                int chunk = t + it*512, row = chunk >> 5, ch = chunk & 31;
                short8 sa = {0,0,0,0,0,0,0,0};
                if (row < NTOK) {
                    const float* pa = x1 + xb + row*256 + ch*8;
                    float4 a0 = *(const float4*)pa, a1 = *(const float4*)(pa+4);
                    sa = pack8(a0, a1);
                }
                *(short8*)((char*)XA + row*512 + ((ch*16) ^ ((row&7)<<4))) = sa;
            }
            __syncthreads();
        }

        // ---- KN GEMM: t16 = 2j+wn, lane-local head-norm ----
        {
            short8 a[8];
#pragma unroll
            for (int kb = 0; kb < 8; ++kb) a[kb] = ld16(XA, 16*wm + lr, kb*32 + lg*8);
            f32x4 ka[8];
#pragma unroll
            for (int j = 0; j < 8; ++j) {
                const int t16 = 2*j + wn;
                const short* bp = wkv + (t16*16 + lr)*256 + lg*8;
                f32x4 acc = {0.f,0.f,0.f,0.f};
#pragma unroll
                for (int kb = 0; kb < 8; ++kb) acc = mfma16(a[kb], g16(bp + kb*32), acc);
                float bj = kvb[t16*16 + lr];
#pragma unroll
                for (int r = 0; r < 4; ++r) acc[r] += bj;
                ka[j] = acc;
            }
#pragma unroll
            for (int r = 0; r < 4; ++r) {
                float s = 0.f;
#pragma unroll
                for (int j = 0; j < 8; ++j) { float v = ka[j][r]; s = fmaf(v, v, s); }
                float rv = 1.0f / fmaxf(sqrtf(s), 1e-12f);
#pragma unroll
                for (int j = 0; j < 8; ++j)
                    st2(KN, 16*wm + 4*lg + r, 32*j + 16*wn + lr, f2b(ka[j][r] * rv));
            }
        }

        // ---- VT GEMM (V^T = Wv @ X^T): 2 col-tiles per wave ----
#pragma unroll
        for (int i = 0; i < 2; ++i) {
            const int c0 = 16*(2*w + i);
            const short* ap = wkv + (256 + c0 + lr)*256 + lg*8;
            short8 aw[8];
#pragma unroll
            for (int kb = 0; kb < 8; ++kb) aw[kb] = g16(ap + kb*32);
            float4 bv4 = *(const float4*)(kvb + 256 + c0 + 4*lg);
            float bvr[4] = {bv4.x, bv4.y, bv4.z, bv4.w};
#pragma unroll
            for (int mt = 0; mt < 4; ++mt) {
                short8 bx[8];
#pragma unroll
                for (int kb = 0; kb < 8; ++kb) bx[kb] = ld16(XA, 16*mt + lr, kb*32 + lg*8);
                f32x4 acc = {0.f,0.f,0.f,0.f};
#pragma unroll
                for (int kb = 0; kb < 8; ++kb) acc = mfma16(aw[kb], bx[kb], acc);
                int m = 16*mt + lr;
                bool val = m < NTOK;
#pragma unroll
                for (int r = 0; r < 4; ++r)
                    st2r128(VT, c0 + 4*lg + r, m, f2b(val ? (acc[r] + bvr[r]) : 0.f));
            }
        }
        __syncthreads();

        // ---- attention: 4 heads per wave ----
        {
            short* Pb = (short*)((char*)XD + 8192 + w*2048);
#pragma unroll 1
            for (int hh = 0; hh < 4; ++hh) {
                const int h = 4*wn + hh;
                short8 aq = ld16(QN, 16*wm + lr, h*32 + lg*8);
                f32x4 s[4];
#pragma unroll
                for (int nt = 0; nt < 4; ++nt) {
                    f32x4 z = {0.f,0.f,0.f,0.f};
                    s[nt] = mfma16(aq, ld16(KN, 16*nt + lr, h*32 + lg*8), z);
                }
                float sv[4][4];
#pragma unroll
                for (int nt = 0; nt < 4; ++nt) {
                    bool msk = (16*nt + lr) >= NTOK;
#pragma unroll
                    for (int r = 0; r < 4; ++r) {
                        float bi = (ri_[nt][r] >= 0) ? rpb[ri_[nt][r]*8 + h] : 0.f;
                        sv[nt][r] = msk ? -1e30f : (s[nt][r] + bi);
                    }
                }
                float isum[4];
#pragma unroll
                for (int r = 0; r < 4; ++r) {
                    float mx = fmaxf(fmaxf(sv[0][r], sv[1][r]), fmaxf(sv[2][r], sv[3][r]));
#pragma unroll
                    for (int d = 1; d < 16; d <<= 1) mx = fmaxf(mx, __shfl_xor(mx, d));
                    float e0 = __expf(sv[0][r]-mx), e1 = __expf(sv[1][r]-mx);
                    float e2 = __expf(sv[2][r]-mx), e3 = __expf(sv[3][r]-mx);
                    float sm = (e0+e1) + (e2+e3);
#pragma unroll
                    for (int d = 1; d < 16; d <<= 1) sm += __shfl_xor(sm, d);
                    isum[r] = 1.0f / sm;
                    int pr = 4*lg + r;
                    st2r128(Pb, pr,      lr, f2b(e0));
                    st2r128(Pb, pr, 16 + lr, f2b(e1));
                    st2r128(Pb, pr, 32 + lr, f2b(e2));
                    st2r128(Pb, pr, 48 + lr, f2b(e3));
                }
                short8 pa0 = ld16r128(Pb, lr, lg*8);
                short8 pa1 = ld16r128(Pb, lr, 32 + lg*8);
#pragma unroll
                for (int nt2 = 0; nt2 < 2; ++nt2) {
                    int crow = h*32 + 16*nt2 + lr;
                    f32x4 acc = {0.f,0.f,0.f,0.f};
                    acc = mfma16(pa0, ld16r128(VT, crow, lg*8), acc);
                    acc = mfma16(pa1, ld16r128(VT, crow, 32 + lg*8), acc);
#pragma unroll
                    for (int r = 0; r < 4; ++r) {
                        int m = 16*wm + 4*lg + r, c = h*32 + 16*nt2 + lr;
                        float qn_ = b2f(*(const short*)((const char*)QN + m*512 + ((c*2) ^ ((m&7)<<4))));
                        float nr = Qn_lds[m*32 + 16*nt2 + lr];
                        float o = acc[r]*isum[r] - qn_*nr*subscale;
                        st2(XA, m, c, f2b(o));
                    }
                }
            }
        }
        __syncthreads();

        // ---- proj GEMM: t16 = 2j+wn ----
        {
            short8 a[8];
#pragma unroll
            for (int kb = 0; kb < 8; ++kb) a[kb] = ld16(XA, 16*wm + lr, kb*32 + lg*8);
#pragma unroll
            for (int j = 0; j < 8; ++j) {
                const int t16 = 2*j + wn;
                const short* bp = wpj + (t16*16 + lr)*256 + lg*8;
                f32x4 acc = {0.f,0.f,0.f,0.f};
#pragma unroll
                for (int kb = 0; kb < 8; ++kb) acc = mfma16(a[kb], g16(bp + kb*32), acc);
                float bj = pjb[t16*16 + lr];
#pragma unroll
                for (int r = 0; r < 4; ++r) {
                    int m = 16*wm + 4*lg + r;
                    if (m < NTOK) outp[(size_t)m*256 + 16*t16 + lr] = acc[r] + bj;
                }
            }
        }
    }
}

extern "C" void kernel_launch(void* const* d_in, const int* in_sizes, int n_in,
                              void* d_out, int out_size, void* d_ws, size_t ws_size,
                              hipStream_t stream) {
    (void)in_sizes; (void)n_in; (void)ws_size; (void)out_size;
    const float* x1   = (const float*)d_in[0];
    const float* x2   = (const float*)d_in[1];
    const int*   rel  = (const int*)  d_in[2];
    const float* kv1w = (const float*)d_in[3];
    const float* kv1b = (const float*)d_in[4];
    const float* kv2w = (const float*)d_in[5];
    const float* kv2b = (const float*)d_in[6];
    const float* qw   = (const float*)d_in[7];
    const float* qb   = (const float*)d_in[8];
    const float* rpb  = (const float*)d_in[9];
    const float* p1w  = (const float*)d_in[10];
    const float* p1b  = (const float*)d_in[11];
    const float* p2w  = (const float*)d_in[12];
    const float* p2b  = (const float*)d_in[13];
    float* out = (float*)d_out;
    short* ws  = (short*)d_ws;

    hipLaunchKernelGGL(prep_w, dim3(TOT_W/256), dim3(256), 0, stream,
                       qw, kv1w, kv2w, p1w, p2w, ws);
    hipLaunchKernelGGL(ta_mfma, dim3(BWIN), dim3(512), 0, stream,
                       x1, x2, rel, kv1b, kv2b, qb, rpb, p1b, p2b,
                       (const short*)ws, out);
}

// Round 4
// 2261.861 us; speedup vs baseline: 2.7570x; 1.0364x over previous
//
#include <hip/hip_runtime.h>
#include <hip/hip_bf16.h>

// TemporalAttention — Round 4: 1024 threads = 16 waves = 4 waves/SIMD (LDS-capped
// at 1 block/CU). Wave w: wm=w&3 (M-tile), wh=w>>2; p=wh&1 (t16 parity), a=wh>>1.
// q/k GEMMs: 4 t16-tiles/wave; cross-head l2-norm completed by partial-sum
// exchange between wave pairs (w, w^8) through LDS. VT: 1 col-tile/wave.
// Attention: 2 heads/wave, two-step PV with 1KB/wave P scratch.
// XD region timeline: [0,8K)=Qn final f32; [8K,24K)=q-partials -> k-partials -> P.

typedef __attribute__((ext_vector_type(8))) short short8;
typedef __attribute__((ext_vector_type(4))) float f32x4;

#define NTOK 49
#define BWIN 4096
#define SCALE 0.17677669529663687f

#define OFF_Q   0
#define OFF_KV1 65536
#define OFF_KV2 196608
#define OFF_P1  327680
#define OFF_P2  393216
#define TOT_W   458752

__device__ __forceinline__ short f2b(float f) {
    union { float f; unsigned u; } v{f};
    unsigned r = v.u + 0x7fffu + ((v.u >> 16) & 1u);   // RNE, inputs never NaN
    return (short)(r >> 16);
}
__device__ __forceinline__ float b2f(short s) {
    return __uint_as_float(((unsigned)(unsigned short)s) << 16);
}
__device__ __forceinline__ short8 pack8(float4 a, float4 b) {
    short8 s;
    s[0]=f2b(a.x); s[1]=f2b(a.y); s[2]=f2b(a.z); s[3]=f2b(a.w);
    s[4]=f2b(b.x); s[5]=f2b(b.y); s[6]=f2b(b.z); s[7]=f2b(b.w);
    return s;
}
__device__ __forceinline__ f32x4 mfma16(short8 a, short8 b, f32x4 c) {
    return __builtin_amdgcn_mfma_f32_16x16x32_bf16(a, b, c, 0, 0, 0);
}
// row-major [64][256] bf16, XOR-swizzled: 16B chunk at (row, c8)
__device__ __forceinline__ short8 ld16(const short* base, int row, int c8) {
    return *(const short8*)((const char*)base + row*512 + ((c8*2) ^ ((row&7)<<4)));
}
__device__ __forceinline__ void st2(short* base, int row, int c, short v) {
    *(short*)((char*)base + row*512 + ((c*2) ^ ((row&7)<<4))) = v;
}
// 128B-stride rows (VT [256][64])
__device__ __forceinline__ short8 ld16r128(const short* base, int row, int m8) {
    return *(const short8*)((const char*)base + row*128 + ((m8*2) ^ ((row&7)<<4)));
}
__device__ __forceinline__ void st2r128(short* base, int row, int m, short v) {
    *(short*)((char*)base + row*128 + ((m*2) ^ ((row&7)<<4))) = v;
}
// P scratch [16][32] bf16, 64B rows, swizzle uses (row>>1)&3 (breaks 4-row aliasing)
__device__ __forceinline__ short8 ld16p(const short* base, int row, int c8) {
    return *(const short8*)((const char*)base + row*64 + ((c8*2) ^ (((row>>1)&3)<<4)));
}
__device__ __forceinline__ void st2p(short* base, int row, int c, short v) {
    *(short*)((char*)base + row*64 + ((c*2) ^ (((row>>1)&3)<<4))) = v;
}
__device__ __forceinline__ short8 g16(const short* p) { return *(const short8*)p; }

__global__ void prep_w(const float* __restrict__ qw, const float* __restrict__ kv1,
                       const float* __restrict__ kv2, const float* __restrict__ p1,
                       const float* __restrict__ p2, short* __restrict__ ws) {
    int i = blockIdx.x * 256 + threadIdx.x;
    float v;
    if      (i < OFF_KV1) v = qw[i];
    else if (i < OFF_KV2) v = kv1[i - OFF_KV1];
    else if (i < OFF_P1)  v = kv2[i - OFF_KV2];
    else if (i < OFF_P2)  v = p1[i - OFF_P1];
    else                  v = p2[i - OFF_P2];
    ws[i] = f2b(v);
}

__global__ __launch_bounds__(1024)
void ta_mfma(const float* __restrict__ x1, const float* __restrict__ x2,
             const int* __restrict__ rel_index,
             const float* __restrict__ kv1_b, const float* __restrict__ kv2_b,
             const float* __restrict__ q_b,  const float* __restrict__ rpb,
             const float* __restrict__ p1_b, const float* __restrict__ p2_b,
             const short* __restrict__ wsbf, float* __restrict__ out)
{
    __shared__ short XA[64*256];   // diff -> x_kv -> o_pre
    __shared__ short XD[64*256];   // [0,8K) Qn f32; [8K,24K) partials / P scratch
    __shared__ short QN[64*256];   // normalized q
    __shared__ short KN[64*256];   // normalized k
    __shared__ short VT[256*64];   // v transposed [c][m]

    const int t  = (int)threadIdx.x;
    const int w  = t >> 6;          // 0..15
    const int wm = w & 3;           // M-tile
    const int wh = w >> 2;          // 0..3
    const int pp = wh & 1;          // t16 parity
    const int aa = wh >> 1;         // pair half (partner wave = w ^ 8)
    const int lr = t & 15;
    const int lg = (t >> 4) & 3;
    const int b  = (int)blockIdx.x;
    const size_t xb = (size_t)b * (NTOK*256);

    float* Qn_lds = (float*)XD;                          // [64][32] f32
    float* Part   = (float*)((char*)XD + 8192);          // [64][32][2] f32

    // ---- stage: XA = bf16(|x2-x1|), pad rows zero ----
#pragma unroll
    for (int it = 0; it < 2; ++it) {
        int chunk = t + it*1024, row = chunk >> 5, ch = chunk & 31;
        short8 sd = {0,0,0,0,0,0,0,0};
        if (row < NTOK) {
            const float* pa = x2 + xb + row*256 + ch*8;
            const float* pc = x1 + xb + row*256 + ch*8;
            float4 a0 = *(const float4*)pa, a1 = *(const float4*)(pa+4);
            float4 c0 = *(const float4*)pc, c1 = *(const float4*)(pc+4);
            float4 d0 = make_float4(fabsf(a0.x-c0.x), fabsf(a0.y-c0.y),
                                    fabsf(a0.z-c0.z), fabsf(a0.w-c0.w));
            float4 d1 = make_float4(fabsf(a1.x-c1.x), fabsf(a1.y-c1.y),
                                    fabsf(a1.z-c1.z), fabsf(a1.w-c1.w));
            sd = pack8(d0, d1);
        }
        *(short8*)((char*)XA + row*512 + ((ch*16) ^ ((row&7)<<4))) = sd;
    }
    __syncthreads();

    // ---- q GEMM: 4 tiles t16 = 8a+2j+p; norm via cross-wave partial exchange ----
    {
        short8 a[8];
#pragma unroll
        for (int kb = 0; kb < 8; ++kb) a[kb] = ld16(XA, 16*wm + lr, kb*32 + lg*8);

        f32x4 qa[4];
        const short* wq = wsbf + OFF_Q;
#pragma unroll
        for (int j = 0; j < 4; ++j) {
            const int t16 = 8*aa + 2*j + pp;
            const short* bp = wq + (t16*16 + lr)*256 + lg*8;
            f32x4 acc = {0.f,0.f,0.f,0.f};
#pragma unroll
            for (int kb = 0; kb < 8; ++kb) acc = mfma16(a[kb], g16(bp + kb*32), acc);
            float bj = q_b[t16*16 + lr];
#pragma unroll
            for (int r = 0; r < 4; ++r) acc[r] = (acc[r] + bj) * SCALE;
            qa[j] = acc;
        }
        float ps[4];
#pragma unroll
        for (int r = 0; r < 4; ++r) {
            float s = 0.f;
#pragma unroll
            for (int j = 0; j < 4; ++j) { float v = qa[j][r]; s = fmaf(v, v, s); }
            ps[r] = s;
            Part[(((16*wm + 4*lg + r)*32) + 16*pp + lr)*2 + aa] = s;
        }
        __syncthreads();     // partials visible; XA diff reads done

        float rin[4];
#pragma unroll
        for (int r = 0; r < 4; ++r) {
            const int row = 16*wm + 4*lg + r, d = 16*pp + lr;
            float tot = ps[r] + Part[((row*32) + d)*2 + (1 - aa)];
            float nr = fmaxf(sqrtf(tot), 1e-12f);
            if (aa == 0) Qn_lds[row*32 + d] = nr;
            rin[r] = 1.0f / nr;
        }
#pragma unroll
        for (int j = 0; j < 4; ++j)
#pragma unroll
            for (int r = 0; r < 4; ++r)
                st2(QN, 16*wm + 4*lg + r, 16*(8*aa + 2*j + pp) + lr, f2b(qa[j][r] * rin[r]));

        // restage XA = bf16(x2) (after the exchange barrier)
#pragma unroll
        for (int it = 0; it < 2; ++it) {
            int chunk = t + it*1024, row = chunk >> 5, ch = chunk & 31;
            short8 sa = {0,0,0,0,0,0,0,0};
            if (row < NTOK) {
                const float* pa = x2 + xb + row*256 + ch*8;
                float4 a0 = *(const float4*)pa, a1 = *(const float4*)(pa+4);
                sa = pack8(a0, a1);
            }
            *(short8*)((char*)XA + row*512 + ((ch*16) ^ ((row&7)<<4))) = sa;
        }
        __syncthreads();
    }

    // rel_index for this wave's rows
    int ri_[4][4];
#pragma unroll
    for (int nt = 0; nt < 4; ++nt)
#pragma unroll
        for (int r = 0; r < 4; ++r) {
            int n = 16*wm + 4*lg + r, mc = 16*nt + lr;
            ri_[nt][r] = (n < NTOK && mc < NTOK) ? rel_index[n*NTOK + mc] : -1;
        }

#pragma unroll 1
    for (int branch = 0; branch < 2; ++branch) {
        const short* wkv = wsbf + (branch ? OFF_KV1 : OFF_KV2);
        const float* kvb = branch ? kv1_b : kv2_b;
        const short* wpj = wsbf + (branch ? OFF_P2 : OFF_P1);
        const float* pjb = branch ? p2_b : p1_b;
        const float subscale = branch ? SCALE : 1.0f;
        float* outp = out + (size_t)branch * ((size_t)BWIN*NTOK*256) + (size_t)b*(NTOK*256);

        if (branch == 1) {
            __syncthreads();           // proj(br0) done reading XA
#pragma unroll
            for (int it = 0; it < 2; ++it) {
                int chunk = t + it*1024, row = chunk >> 5, ch = chunk & 31;
                short8 sa = {0,0,0,0,0,0,0,0};
                if (row < NTOK) {
                    const float* pa = x1 + xb + row*256 + ch*8;
                    float4 a0 = *(const float4*)pa, a1 = *(const float4*)(pa+4);
                    sa = pack8(a0, a1);
                }
                *(short8*)((char*)XA + row*512 + ((ch*16) ^ ((row&7)<<4))) = sa;
            }
            __syncthreads();
        }

        // ---- KN GEMM: 4 tiles, cross-wave norm exchange ----
        {
            short8 a[8];
#pragma unroll
            for (int kb = 0; kb < 8; ++kb) a[kb] = ld16(XA, 16*wm + lr, kb*32 + lg*8);
            f32x4 ka[4];
#pragma unroll
            for (int j = 0; j < 4; ++j) {
                const int t16 = 8*aa + 2*j + pp;
                const short* bp = wkv + (t16*16 + lr)*256 + lg*8;
                f32x4 acc = {0.f,0.f,0.f,0.f};
#pragma unroll
                for (int kb = 0; kb < 8; ++kb) acc = mfma16(a[kb], g16(bp + kb*32), acc);
                float bj = kvb[t16*16 + lr];
#pragma unroll
                for (int r = 0; r < 4; ++r) acc[r] += bj;
                ka[j] = acc;
            }
            float ps[4];
#pragma unroll
            for (int r = 0; r < 4; ++r) {
                float s = 0.f;
#pragma unroll
                for (int j = 0; j < 4; ++j) { float v = ka[j][r]; s = fmaf(v, v, s); }
                ps[r] = s;
                Part[(((16*wm + 4*lg + r)*32) + 16*pp + lr)*2 + aa] = s;
            }
            __syncthreads();
#pragma unroll
            for (int r = 0; r < 4; ++r) {
                const int row = 16*wm + 4*lg + r, d = 16*pp + lr;
                float tot = ps[r] + Part[((row*32) + d)*2 + (1 - aa)];
                float rv = 1.0f / fmaxf(sqrtf(tot), 1e-12f);
#pragma unroll
                for (int j = 0; j < 4; ++j)
                    st2(KN, row, 16*(8*aa + 2*j + pp) + lr, f2b(ka[j][r] * rv));
            }
        }

        // ---- VT GEMM (V^T = Wv @ X^T): 1 col-tile per wave ----
        {
            const int c0 = 16*w;
            const short* ap = wkv + (256 + c0 + lr)*256 + lg*8;
            short8 aw[8];
#pragma unroll
            for (int kb = 0; kb < 8; ++kb) aw[kb] = g16(ap + kb*32);
            float4 bv4 = *(const float4*)(kvb + 256 + c0 + 4*lg);
            float bvr[4] = {bv4.x, bv4.y, bv4.z, bv4.w};
#pragma unroll
            for (int mt = 0; mt < 4; ++mt) {
                short8 bx[8];
#pragma unroll
                for (int kb = 0; kb < 8; ++kb) bx[kb] = ld16(XA, 16*mt + lr, kb*32 + lg*8);
                f32x4 acc = {0.f,0.f,0.f,0.f};
#pragma unroll
                for (int kb = 0; kb < 8; ++kb) acc = mfma16(aw[kb], bx[kb], acc);
                int m = 16*mt + lr;
                bool val = m < NTOK;
#pragma unroll
                for (int r = 0; r < 4; ++r)
                    st2r128(VT, c0 + 4*lg + r, m, f2b(val ? (acc[r] + bvr[r]) : 0.f));
            }
        }
        __syncthreads();

        // ---- attention: 2 heads per wave, two-step PV ----
        {
            short* Pb = (short*)((char*)XD + 8192 + w*1024);
#pragma unroll 1
            for (int hh = 0; hh < 2; ++hh) {
                const int h = 2*wh + hh;
                short8 aq = ld16(QN, 16*wm + lr, h*32 + lg*8);
                f32x4 s[4];
#pragma unroll
                for (int nt = 0; nt < 4; ++nt) {
                    f32x4 z = {0.f,0.f,0.f,0.f};
                    s[nt] = mfma16(aq, ld16(KN, 16*nt + lr, h*32 + lg*8), z);
                }
                float sv[4][4];
#pragma unroll
                for (int nt = 0; nt < 4; ++nt) {
                    bool msk = (16*nt + lr) >= NTOK;
#pragma unroll
                    for (int r = 0; r < 4; ++r) {
                        float bi = (ri_[nt][r] >= 0) ? rpb[ri_[nt][r]*8 + h] : 0.f;
                        sv[nt][r] = msk ? -1e30f : (s[nt][r] + bi);
                    }
                }
                float isum[4], e2a[4], e3a[4];
#pragma unroll
                for (int r = 0; r < 4; ++r) {
                    float mx = fmaxf(fmaxf(sv[0][r], sv[1][r]), fmaxf(sv[2][r], sv[3][r]));
#pragma unroll
                    for (int d = 1; d < 16; d <<= 1) mx = fmaxf(mx, __shfl_xor(mx, d));
                    float e0 = __expf(sv[0][r]-mx), e1 = __expf(sv[1][r]-mx);
                    float e2 = __expf(sv[2][r]-mx), e3 = __expf(sv[3][r]-mx);
                    float sm = (e0+e1) + (e2+e3);
#pragma unroll
                    for (int d = 1; d < 16; d <<= 1) sm += __shfl_xor(sm, d);
                    isum[r] = 1.0f / sm;
                    int pr = 4*lg + r;
                    st2p(Pb, pr,      lr, f2b(e0));
                    st2p(Pb, pr, 16 + lr, f2b(e1));
                    e2a[r] = e2; e3a[r] = e3;
                }
                short8 pa0 = ld16p(Pb, lr, lg*8);
                f32x4 acc0 = {0.f,0.f,0.f,0.f}, acc1 = {0.f,0.f,0.f,0.f};
                acc0 = mfma16(pa0, ld16r128(VT, h*32 + lr,      lg*8), acc0);
                acc1 = mfma16(pa0, ld16r128(VT, h*32 + 16 + lr, lg*8), acc1);
#pragma unroll
                for (int r = 0; r < 4; ++r) {
                    int pr = 4*lg + r;
                    st2p(Pb, pr,      lr, f2b(e2a[r]));
                    st2p(Pb, pr, 16 + lr, f2b(e3a[r]));
                }
                short8 pa1 = ld16p(Pb, lr, lg*8);
                acc0 = mfma16(pa1, ld16r128(VT, h*32 + lr,      32 + lg*8), acc0);
                acc1 = mfma16(pa1, ld16r128(VT, h*32 + 16 + lr, 32 + lg*8), acc1);
#pragma unroll
                for (int nt2 = 0; nt2 < 2; ++nt2) {
                    f32x4 acc = nt2 ? acc1 : acc0;
#pragma unroll
                    for (int r = 0; r < 4; ++r) {
                        int m = 16*wm + 4*lg + r, c = h*32 + 16*nt2 + lr;
                        float qn_ = b2f(*(const short*)((const char*)QN + m*512 + ((c*2) ^ ((m&7)<<4))));
                        float nr2 = Qn_lds[m*32 + 16*nt2 + lr];
                        float o = acc[r]*isum[r] - qn_*nr2*subscale;
                        st2(XA, m, c, f2b(o));
                    }
                }
            }
        }
        __syncthreads();

        // ---- proj GEMM: t16 = 4j + wh ----
        {
            short8 a[8];
#pragma unroll
            for (int kb = 0; kb < 8; ++kb) a[kb] = ld16(XA, 16*wm + lr, kb*32 + lg*8);
#pragma unroll
            for (int j = 0; j < 4; ++j) {
                const int t16 = 4*j + wh;
                const short* bp = wpj + (t16*16 + lr)*256 + lg*8;
                f32x4 acc = {0.f,0.f,0.f,0.f};
#pragma unroll
                for (int kb = 0; kb < 8; ++kb) acc = mfma16(a[kb], g16(bp + kb*32), acc);
                float bj = pjb[t16*16 + lr];
#pragma unroll
                for (int r = 0; r < 4; ++r) {
                    int m = 16*wm + 4*lg + r;
                    if (m < NTOK) outp[(size_t)m*256 + 16*t16 + lr] = acc[r] + bj;
                }
            }
        }
    }
}

extern "C" void kernel_launch(void* const* d_in, const int* in_sizes, int n_in,
                              void* d_out, int out_size, void* d_ws, size_t ws_size,
                              hipStream_t stream) {
    (void)in_sizes; (void)n_in; (void)ws_size; (void)out_size;
    const float* x1   = (const float*)d_in[0];
    const float* x2   = (const float*)d_in[1];
    const int*   rel  = (const int*)  d_in[2];
    const float* kv1w = (const float*)d_in[3];
    const float* kv1b = (const float*)d_in[4];
    const float* kv2w = (const float*)d_in[5];
    const float* kv2b = (const float*)d_in[6];
    const float* qw   = (const float*)d_in[7];
    const float* qb   = (const float*)d_in[8];
    const float* rpb  = (const float*)d_in[9];
    const float* p1w  = (const float*)d_in[10];
    const float* p1b  = (const float*)d_in[11];
    const float* p2w  = (const float*)d_in[12];
    const float* p2b  = (const float*)d_in[13];
    float* out = (float*)d_out;
    short* ws  = (short*)d_ws;

    hipLaunchKernelGGL(prep_w, dim3(TOT_W/256), dim3(256), 0, stream,
                       qw, kv1w, kv2w, p1w, p2w, ws);
    hipLaunchKernelGGL(ta_mfma, dim3(BWIN), dim3(1024), 0, stream,
                       x1, x2, rel, kv1b, kv2b, qb, rpb, p1b, p2b,
                       (const short*)ws, out);
}